// Round 10
// baseline (7978.954 us; speedup 1.0000x reference)
//
#include <hip/hip_runtime.h>
#include <math.h>

#define TT 400
#define BBATCH 256
#define VDIM 128
#define CDIM 64
#define HDIM 512
#define NCHUNK 11   // 11 rounds x 64 k (2 k-halves of 32)
#define P1B 1024    // phase-1 blocks; phase-2 blocks are P1B..P1B+255

typedef double d4 __attribute__((ext_vector_type(4)));

__device__ __forceinline__ double sigd(double x) {
  if (x >= 0.0) { double e = exp(-x); return 1.0 / (1.0 + e); }
  double e = exp(x); return e / (1.0 + e);
}

// transpose W_out/W_ctrl to [k][c]; init rowlive/alive/done.
__global__ __launch_bounds__(256) void k_init(
    float* __restrict__ wtro, const float* __restrict__ W_out,
    float* __restrict__ wtrc, const float* __restrict__ W_ctrl,
    int* __restrict__ rowlive, int* __restrict__ alive, int* __restrict__ done)
{
  const int i = blockIdx.x * 256 + threadIdx.x;
  if (i < HDIM * CDIM) {
    const int k = i >> 6, c = i & 63;
    wtro[i] = W_out[c * HDIM + k];
  }
  if (i < 577 * CDIM) {
    const int k = i >> 6, c = i & 63;
    wtrc[i] = W_ctrl[c * 577 + k];
  }
  if (i < BBATCH) rowlive[i] = 1;
  if (i < TT) alive[i] = 0;
  if (i < TT * 16) done[i] = 0;
}

// One launch per step. Blocks 0..1023: gates GEMM (f64 MFMA) + LSTM cell
// (grid-role (cb=bid&63, rb=bid>>6), 16 rows x 32 gate-cols, 4 waves =
// 2 col-tiles x 2 k-halves, ~34 KB LDS -> 4 blocks/CU). Blocks 1024..1279:
// phase 2 for row b = bid-1024, spin-waiting on done[t*16 + b>>4] == 64
// (device-scope release by producers / acquire by consumer, G16 pattern).
__global__ __launch_bounds__(256, 4) void k_step(
    const float* __restrict__ X, const float* __restrict__ W_ih,
    const float* __restrict__ W_hh, const float* __restrict__ b_ih,
    const float* __restrict__ b_hh, const float* __restrict__ wtro,
    const float* __restrict__ b_out, const float* __restrict__ wtrc,
    const float* __restrict__ b_ctrl, const float* __restrict__ noise,
    const int* __restrict__ epoch_p, const double* __restrict__ hR,
    double* __restrict__ hW, double* __restrict__ cst,
    double* __restrict__ ybar, double* __restrict__ preds,
    float* __restrict__ halt, double* __restrict__ ylast,
    int* __restrict__ rowlive, int* __restrict__ alive,
    int* __restrict__ done, int t)
{
  const int tid  = threadIdx.x;
  const int lane = tid & 63;
  const int bid  = blockIdx.x;
  if (t > 0 && alive[t - 1] == 0) return;      // dead step: everyone leaves

  // A fragments f64: [buf][kh][slot][16*j + row]  (pad 66)
  // B fragments f32: [buf][kh][ct][slot][col*4+j] (pad 68)
  // phase-2 arrays alias into aF (1088 of 2112 doubles used)
  __shared__ __align__(16) double aF[2][2][8][66];      // 16.9 KB
  __shared__ __align__(16) float  bF[2][2][2][8][68];   // 17.4 KB

  if (bid < P1B) {
    // ======================= PHASE 1 =======================
    const int wid  = tid >> 6;
    const int cb   = bid & 63;
    const int rb   = bid >> 6;
    const int r0   = rb * 16;
    const int hbase = cb * 8;

    if (t > 0) {   // group skip: all 16 rows halted -> outputs never read
      const unsigned long long m =
          __ballot((lane < 16) && (rowlive[r0 + (lane & 15)] != 0));
      if (m == 0ull) {
        if (tid == 0) atomicAdd(&done[t * 16 + rb], 1);
        return;
      }
    }

    double* gsp = &aF[0][0][0][0];   // gate staging aliases aF after k-loop

    const int sA  = tid & 7;          // k-slot
    const int khA = (tid >> 3) & 1;   // k-half
    const int rrA = tid >> 4;         // 0..15: A row / B col

    // Empirical f64-MFMA D-layout probe (see R3 note): decode reg->row/col.
    int rowm[4], colm[4];
    {
      d4 dp = {0.0, 0.0, 0.0, 0.0};
      const double ap = (lane < 16) ? (double)(lane + 1) : (lane < 32 ? 1.0 : 0.0);
      const double bp = (lane < 16) ? 1.0
                      : (lane < 32 ? 1000.0 * (double)((lane & 15) + 1) : 0.0);
      dp = __builtin_amdgcn_mfma_f64_16x16x4f64(ap, bp, dp, 0, 0, 0);
      #pragma unroll
      for (int r = 0; r < 4; ++r) {
        const int iv = (int)(dp[r] + 0.5);
        rowm[r] = ((iv % 1000) - 1) & 15;
        colm[r] = ((iv / 1000) - 1) & 15;
      }
    }

    double pa[4];
    float4 pw0, pw1;
    const int c0 = rrA, c1 = 16 + rrA;
    const int wg0 = (c0 >> 3) * HDIM + hbase + (c0 & 7);
    const int wg1 = (c1 >> 3) * HDIM + hbase + (c1 & 7);

    auto load_to = [&](int ci) {
      const int kk = ci * 64 + khA * 32 + sA * 4;
      const int rr = r0 + rrA;
      if (kk < VDIM) {
        const float4 v = *(const float4*)(X + ((size_t)t * BBATCH + rr) * VDIM + kk);
        pa[0] = v.x; pa[1] = v.y; pa[2] = v.z; pa[3] = v.w;
      } else if (t == 0) {
        pa[0] = 0.0; pa[1] = 0.0; pa[2] = 0.0; pa[3] = 0.0;
      } else if (kk < VDIM + CDIM) {
        const double2 v0 = *(const double2*)(ybar + (size_t)rr * CDIM + (kk - VDIM));
        const double2 v1 = *(const double2*)(ybar + (size_t)rr * CDIM + (kk - VDIM) + 2);
        pa[0] = v0.x; pa[1] = v0.y; pa[2] = v1.x; pa[3] = v1.y;
      } else {
        const double2 v0 = *(const double2*)(hR + (size_t)rr * HDIM + (kk - 192));
        const double2 v1 = *(const double2*)(hR + (size_t)rr * HDIM + (kk - 192) + 2);
        pa[0] = v0.x; pa[1] = v0.y; pa[2] = v1.x; pa[3] = v1.y;
      }
      pw0 = (kk < 192) ? *(const float4*)(W_ih + (size_t)wg0 * 192 + kk)
                       : *(const float4*)(W_hh + (size_t)wg0 * HDIM + (kk - 192));
      pw1 = (kk < 192) ? *(const float4*)(W_ih + (size_t)wg1 * 192 + kk)
                       : *(const float4*)(W_hh + (size_t)wg1 * HDIM + (kk - 192));
    };
    auto store_to = [&](int buf) {
      #pragma unroll
      for (int j = 0; j < 4; ++j)
        aF[buf][khA][sA][16 * j + rrA] = pa[j];
      *(float4*)&bF[buf][khA][0][sA][rrA * 4] = pw0;
      *(float4*)&bF[buf][khA][1][sA][rrA * 4] = pw1;
    };

    const int ct = tid >> 6 & 1, kh = wid >> 1;   // wave role
    d4 aa = {0.0, 0.0, 0.0, 0.0}, ab = aa;

    load_to(0);
    store_to(0);
    __syncthreads();

    for (int ci = 0; ci < NCHUNK; ++ci) {
      const int p = ci & 1;
      if (ci + 1 < NCHUNK) load_to(ci + 1);
      #pragma unroll
      for (int ss = 0; ss < 8; ++ss) {
        const double av = aF[p][kh][ss][lane];
        const double bv = (double)bF[p][kh][ct][ss][(lane & 15) * 4 + (lane >> 4)];
        if (ss & 1) ab = __builtin_amdgcn_mfma_f64_16x16x4f64(av, bv, ab, 0, 0, 0);
        else        aa = __builtin_amdgcn_mfma_f64_16x16x4f64(av, bv, aa, 0, 0, 0);
      }
      if (ci + 1 < NCHUNK) store_to(p ^ 1);
      __syncthreads();
    }
    const d4 acc = aa + ab;

    #pragma unroll
    for (int r = 0; r < 4; ++r)
      gsp[kh * 528 + rowm[r] * 33 + 16 * ct + colm[r]] = acc[r];
    __syncthreads();

    if (tid < 128) {
      const int jj = tid & 7, r = tid >> 3;
      const int g0 = hbase + jj;
      const double gi = gsp[r * 33 + jj]      + gsp[528 + r * 33 + jj]
                      + (double)b_ih[0 * HDIM + g0] + (double)b_hh[0 * HDIM + g0];
      const double gf = gsp[r * 33 + 8 + jj]  + gsp[528 + r * 33 + 8 + jj]
                      + (double)b_ih[1 * HDIM + g0] + (double)b_hh[1 * HDIM + g0];
      const double gg = gsp[r * 33 + 16 + jj] + gsp[528 + r * 33 + 16 + jj]
                      + (double)b_ih[2 * HDIM + g0] + (double)b_hh[2 * HDIM + g0];
      const double go = gsp[r * 33 + 24 + jj] + gsp[528 + r * 33 + 24 + jj]
                      + (double)b_ih[3 * HDIM + g0] + (double)b_hh[3 * HDIM + g0];
      const size_t oidx = (size_t)(r0 + r) * HDIM + g0;
      const double cold = (t == 0) ? 0.0 : cst[oidx];
      const double cn = sigd(gf) * cold + sigd(gi) * tanh(gg);
      const double hn = sigd(go) * tanh(cn);
      cst[oidx] = cn;
      hW[oidx]  = hn;
    }

    __syncthreads();                       // all hW stores issued
    if (tid == 0) {
      __threadfence();                     // release to device scope
      atomicAdd(&done[t * 16 + rb], 1);
    }
  } else {
    // ======================= PHASE 2 =======================
    const int b = bid - P1B;
    if (t > 0 && rowlive[b] == 0) return;

    if (tid == 0) {                        // acquire: group producers done
      while (atomicAdd(&done[t * 16 + (b >> 4)], 0) < 64)
        __builtin_amdgcn_s_sleep(2);
      __threadfence();
    }
    __syncthreads();

    double* hsh = &aF[0][0][0][0];         // 512
    double* p1  = hsh + HDIM;              // 256
    double* p2  = p1 + 256;                // 256
    double* ysh = p2 + 256;                // 64   (1088 <= 2112 doubles)

    *(double2*)&hsh[2 * tid] = *(const double2*)(hW + (size_t)b * HDIM + 2 * tid);
    __syncthreads();

    const int c = tid & 63, kq = tid >> 6;
    const int k0 = kq * 128;

    double s1 = 0.0, s2 = 0.0;
    #pragma unroll 8
    for (int k = k0; k < k0 + 128; ++k) {
      const double hk = hsh[k];
      s1 += hk * (double)wtro[k * 64 + c];
      s2 += hk * (double)wtrc[k * 64 + c];
    }
    p1[kq * 64 + c] = s1;
    p2[kq * 64 + c] = s2;
    __syncthreads();

    if (tid < 64)
      ysh[tid] = sigd(p1[tid] + p1[64 + tid] + p1[128 + tid] + p1[192 + tid]
                      + (double)b_out[tid]);
    __syncthreads();

    if (tid < 64) {
      double a2 = p2[tid] + p2[64 + tid] + p2[128 + tid] + p2[192 + tid];
      #pragma unroll 8
      for (int j = 0; j < CDIM; ++j)
        a2 += ysh[j] * (double)wtrc[(512 + j) * 64 + tid];
      a2 += (double)t * (double)wtrc[576 * 64 + tid] + (double)b_ctrl[tid];

      const double eps = exp(-7.0 * (double)(*epoch_p) / 99.0);
      const double pr  = (1.0 - eps) * sigd(a2) + eps * 0.05;
      const double n   = (double)noise[((size_t)t * BBATCH + b) * CDIM + tid];
      const bool   at  = n < pr;
      const double yh  = ysh[tid];
      const size_t i   = (size_t)b * CDIM + tid;

      const double pred_old = (t == 0) ? 0.0  : preds[i];
      const double ybar_old = (t == 0) ? 0.0  : ybar[i];
      const float  halt_old = (t == 0) ? -1.0f : halt[i];

      const double pred_new = (at && pred_old == 0.0) ? yh : pred_old;
      preds[i] = pred_new;
      ybar[i]  = (at && ybar_old == 0.0) ? 1.0 : ybar_old;
      halt[i]  = (halt_old == -1.0f && at) ? (float)t : halt_old;
      ylast[i] = yh;

      const unsigned long long m = __ballot(pred_new == 0.0);
      if (tid == 0) {
        rowlive[b] = (m != 0ull) ? 1 : 0;
        if (m != 0ull) atomicOr(alive + t, 1);
      }
    }
  }
}

__global__ __launch_bounds__(256) void k_final_out(
    const double* __restrict__ preds, const double* __restrict__ ylast,
    float* __restrict__ out)
{
  const int i = blockIdx.x * 256 + threadIdx.x;
  const double p = preds[i];
  out[i] = (float)(p == 0.0 ? ylast[i] : p);
}

__global__ __launch_bounds__(256) void k_final_mean(
    const float* __restrict__ halt, float* __restrict__ out)
{
  __shared__ double s[256];
  double acc = 0.0;
  for (int i = threadIdx.x; i < BBATCH * CDIM; i += 256) {
    const float hp = halt[i];
    acc += 1.0 + (hp == -1.0f ? (double)(TT - 1) : (double)hp);
  }
  s[threadIdx.x] = acc;
  __syncthreads();
  for (int off = 128; off > 0; off >>= 1) {
    if (threadIdx.x < off) s[threadIdx.x] += s[threadIdx.x + off];
    __syncthreads();
  }
  if (threadIdx.x == 0)
    out[BBATCH * CDIM] = (float)(s[0] / (double)(BBATCH * CDIM) / (double)(TT + 1));
}

extern "C" void kernel_launch(void* const* d_in, const int* in_sizes, int n_in,
                              void* d_out, int out_size, void* d_ws, size_t ws_size,
                              hipStream_t stream)
{
  const float* X      = (const float*)d_in[0];
  const float* noise  = (const float*)d_in[1];
  const float* W_ih   = (const float*)d_in[2];
  const float* W_hh   = (const float*)d_in[3];
  const float* b_ih   = (const float*)d_in[4];
  const float* b_hh   = (const float*)d_in[5];
  const float* W_out  = (const float*)d_in[6];
  const float* b_out  = (const float*)d_in[7];
  const float* W_ctrl = (const float*)d_in[8];
  const float* b_ctrl = (const float*)d_in[9];
  const int*   epoch  = (const int*)d_in[10];
  float* out = (float*)d_out;

  char* ws = (char*)d_ws;
  double* h0      = (double*)ws;
  double* h1      = h0    + (size_t)BBATCH * HDIM;
  double* cst     = h1    + (size_t)BBATCH * HDIM;
  double* ybar    = cst   + (size_t)BBATCH * HDIM;
  double* preds   = ybar  + (size_t)BBATCH * CDIM;
  double* ylast   = preds + (size_t)BBATCH * CDIM;
  float*  halt    = (float*)(ylast + (size_t)BBATCH * CDIM);
  float*  wtro    = halt + (size_t)BBATCH * CDIM;
  float*  wtrc    = wtro + (size_t)HDIM * CDIM;
  int*    rowlive = (int*)(wtrc + (size_t)577 * CDIM);
  int*    alive   = rowlive + BBATCH;
  int*    done    = alive + TT;

  k_init<<<145, 256, 0, stream>>>(wtro, W_out, wtrc, W_ctrl, rowlive, alive, done);

  for (int t = 0; t < TT; ++t) {
    const double* hR = (t & 1) ? h1 : h0;
    double*       hW = (t & 1) ? h0 : h1;
    k_step<<<P1B + BBATCH, 256, 0, stream>>>(
        X, W_ih, W_hh, b_ih, b_hh, wtro, b_out, wtrc, b_ctrl, noise, epoch,
        hR, hW, cst, ybar, preds, halt, ylast, rowlive, alive, done, t);
  }

  k_final_out<<<64, 256, 0, stream>>>(preds, ylast, out);
  k_final_mean<<<1, 256, 0, stream>>>(halt, out);
}

// Round 11
// 4231.719 us; speedup vs baseline: 1.8855x; 1.8855x over previous
//
#include <hip/hip_runtime.h>
#include <math.h>

#define TT 400
#define BBATCH 256
#define VDIM 128
#define CDIM 64
#define HDIM 512
#define NCHUNK 11   // 11 chunks x 64 k (2 k-halves of 32)

typedef double d4 __attribute__((ext_vector_type(4)));

__device__ __forceinline__ double sigd(double x) {
  if (x >= 0.0) { double e = exp(-x); return 1.0 / (1.0 + e); }
  double e = exp(x); return e / (1.0 + e);
}

// transpose W_out/W_ctrl to [k][c]; init rowlive/alive. All other state is
// (re)initialized inside the step kernels via t==0 guards.
__global__ __launch_bounds__(256) void k_init(
    float* __restrict__ wtro, const float* __restrict__ W_out,
    float* __restrict__ wtrc, const float* __restrict__ W_ctrl,
    int* __restrict__ rowlive, int* __restrict__ alive)
{
  const int i = blockIdx.x * 256 + threadIdx.x;
  if (i < HDIM * CDIM) {
    const int k = i >> 6, c = i & 63;
    wtro[i] = W_out[c * HDIM + k];
  }
  if (i < 577 * CDIM) {
    const int k = i >> 6, c = i & 63;
    wtrc[i] = W_ctrl[c * 577 + k];
  }
  if (i < BBATCH) rowlive[i] = 1;
  if (i < TT) alive[i] = 0;
}

// Phase 1: gates GEMM (f64 MFMA) + fused LSTM cell.
// Grid (64,16): 64 col-blocks (32 gate-cols) x 16 row-blocks (16 rows).
// 4 waves = 2 col-tiles x 2 k-halves; ~34 KB LDS -> 4 blocks/CU.
// Chunk->source mapping is static (0-1: X, 2: ybar, 3-10: h), so the staging
// pipeline is specialized into three branch-free regions.
__global__ __launch_bounds__(256, 4) void k_phase1(
    const float* __restrict__ X, const float* __restrict__ W_ih,
    const float* __restrict__ W_hh, const float* __restrict__ b_ih,
    const float* __restrict__ b_hh, const double* __restrict__ hR,
    double* __restrict__ hW, double* __restrict__ cst,
    const double* __restrict__ ybar, const int* __restrict__ rowlive,
    const int* __restrict__ alive, int t)
{
  if (t > 0 && alive[t - 1] == 0) return;      // everything halted: dead step

  const int tid  = threadIdx.x;
  const int lane = tid & 63;
  const int wid  = tid >> 6;
  const int cb   = blockIdx.x;
  const int rb   = blockIdx.y;
  const int r0   = rb * 16;
  const int hbase = cb * 8;

  // 16-row block skip: all rows halted -> outputs never read
  if (t > 0) {
    const unsigned long long m =
        __ballot((lane < 16) && (rowlive[r0 + (lane & 15)] != 0));
    if (m == 0ull) return;
  }

  // A fragments f64: [buf][kh][slot][16*j + row]  (pad 66)
  // B fragments f32: [buf][kh][ct][slot][col*4+j] (pad 68)
  __shared__ __align__(16) double aF[2][2][8][66];      // 16.9 KB
  __shared__ __align__(16) float  bF[2][2][2][8][68];   // 17.4 KB
  double* gsp = &aF[0][0][0][0];   // gate staging aliases aF after the k-loop

  const int sA  = tid & 7;          // k-slot
  const int khA = (tid >> 3) & 1;   // k-half
  const int rrA = tid >> 4;         // 0..15: A row / B col

  // Empirical f64-MFMA D-layout probe: A[i][0]=i+1,A[i][1]=1,B[0][j]=1,
  // B[1][j]=1000(j+1) => D[i][j]=(i+1)+1000(j+1); decode reg->row/col.
  int rowm[4], colm[4];
  {
    d4 dp = {0.0, 0.0, 0.0, 0.0};
    const double ap = (lane < 16) ? (double)(lane + 1) : (lane < 32 ? 1.0 : 0.0);
    const double bp = (lane < 16) ? 1.0
                    : (lane < 32 ? 1000.0 * (double)((lane & 15) + 1) : 0.0);
    dp = __builtin_amdgcn_mfma_f64_16x16x4f64(ap, bp, dp, 0, 0, 0);
    #pragma unroll
    for (int r = 0; r < 4; ++r) {
      const int iv = (int)(dp[r] + 0.5);
      rowm[r] = ((iv % 1000) - 1) & 15;
      colm[r] = ((iv / 1000) - 1) & 15;
    }
  }

  double pa[4];
  float4 pw0, pw1;

  // hoisted per-thread invariant bases
  const int rr   = r0 + rrA;
  const int kloc = khA * 32 + sA * 4;                    // k within chunk
  const int c0 = rrA, c1 = 16 + rrA;
  const int wg0 = (c0 >> 3) * HDIM + hbase + (c0 & 7);
  const int wg1 = (c1 >> 3) * HDIM + hbase + (c1 & 7);
  const float*  Xbase = X + ((size_t)t * BBATCH + rr) * VDIM + kloc;
  const double* Ybase = ybar + (size_t)rr * CDIM + (kloc);        // chunk2: kk-128 = kloc
  const double* Hbase = hR + (size_t)rr * HDIM + kloc;            // chunk ci: + ci*64-192
  const float*  Wih0  = W_ih + (size_t)wg0 * 192 + kloc;
  const float*  Wih1  = W_ih + (size_t)wg1 * 192 + kloc;
  const float*  Whh0  = W_hh + (size_t)wg0 * HDIM + kloc;
  const float*  Whh1  = W_hh + (size_t)wg1 * HDIM + kloc;

  auto load_X = [&](int ci) {            // chunks 0,1 (kk < 128)
    const float4 v = *(const float4*)(Xbase + ci * 64);
    pa[0] = v.x; pa[1] = v.y; pa[2] = v.z; pa[3] = v.w;
    pw0 = *(const float4*)(Wih0 + ci * 64);
    pw1 = *(const float4*)(Wih1 + ci * 64);
  };
  auto load_Y = [&]() {                  // chunk 2 (128 <= kk < 192)
    if (t == 0) {
      pa[0] = 0.0; pa[1] = 0.0; pa[2] = 0.0; pa[3] = 0.0;
    } else {
      const double2 v0 = *(const double2*)(Ybase);
      const double2 v1 = *(const double2*)(Ybase + 2);
      pa[0] = v0.x; pa[1] = v0.y; pa[2] = v1.x; pa[3] = v1.y;
    }
    pw0 = *(const float4*)(Wih0 + 128);
    pw1 = *(const float4*)(Wih1 + 128);
  };
  auto load_H = [&](int ci) {            // chunks 3..10 (kk >= 192)
    if (t == 0) {
      pa[0] = 0.0; pa[1] = 0.0; pa[2] = 0.0; pa[3] = 0.0;
    } else {
      const double2 v0 = *(const double2*)(Hbase + ci * 64 - 192);
      const double2 v1 = *(const double2*)(Hbase + ci * 64 - 192 + 2);
      pa[0] = v0.x; pa[1] = v0.y; pa[2] = v1.x; pa[3] = v1.y;
    }
    pw0 = *(const float4*)(Whh0 + ci * 64 - 192);
    pw1 = *(const float4*)(Whh1 + ci * 64 - 192);
  };
  auto store_to = [&](int buf) {
    #pragma unroll
    for (int j = 0; j < 4; ++j)
      aF[buf][khA][sA][16 * j + rrA] = pa[j];
    *(float4*)&bF[buf][khA][0][sA][rrA * 4] = pw0;
    *(float4*)&bF[buf][khA][1][sA][rrA * 4] = pw1;
  };

  const int ct = wid & 1, kh = wid >> 1;   // wave role
  const int bidx = (lane & 15) * 4 + (lane >> 4);
  d4 aa = {0.0, 0.0, 0.0, 0.0}, ab = aa;

  // software-pipelined MFMA over the 8 k-slots of one staged buffer
  auto mfma_chunk = [&](int p) {
    double av = aF[p][kh][0][lane];
    double bv = (double)bF[p][kh][ct][0][bidx];
    #pragma unroll
    for (int ss = 0; ss < 8; ++ss) {
      double avn = 0.0, bvn = 0.0;
      if (ss < 7) {
        avn = aF[p][kh][ss + 1][lane];
        bvn = (double)bF[p][kh][ct][ss + 1][bidx];
      }
      if (ss & 1) ab = __builtin_amdgcn_mfma_f64_16x16x4f64(av, bv, ab, 0, 0, 0);
      else        aa = __builtin_amdgcn_mfma_f64_16x16x4f64(av, bv, aa, 0, 0, 0);
      av = avn; bv = bvn;
    }
  };

  // region-specialized pipeline: compute ci uses buf ci&1, prefetch ci+1
  load_X(0); store_to(0); __syncthreads();
  load_X(1); mfma_chunk(0); store_to(1); __syncthreads();   // ci=0
  load_Y();  mfma_chunk(1); store_to(0); __syncthreads();   // ci=1
  load_H(3); mfma_chunk(0); store_to(1); __syncthreads();   // ci=2
  for (int ci = 3; ci < NCHUNK - 1; ++ci) {                 // ci=3..9
    load_H(ci + 1);
    mfma_chunk(ci & 1);
    store_to((ci + 1) & 1);
    __syncthreads();
  }
  mfma_chunk(0);                                            // ci=10
  const d4 acc = aa + ab;

  __syncthreads();   // aF reads done before gsp aliasing writes
  #pragma unroll
  for (int r = 0; r < 4; ++r)
    gsp[kh * 528 + rowm[r] * 33 + 16 * ct + colm[r]] = acc[r];
  __syncthreads();

  // LSTM cell: 16 rows x 8 hidden = 128 pairs; k-halves summed in fixed order.
  if (tid < 128) {
    const int jj = tid & 7, r = tid >> 3;
    const int g0 = hbase + jj;
    const double gi = gsp[r * 33 + jj]      + gsp[528 + r * 33 + jj]
                    + (double)b_ih[0 * HDIM + g0] + (double)b_hh[0 * HDIM + g0];
    const double gf = gsp[r * 33 + 8 + jj]  + gsp[528 + r * 33 + 8 + jj]
                    + (double)b_ih[1 * HDIM + g0] + (double)b_hh[1 * HDIM + g0];
    const double gg = gsp[r * 33 + 16 + jj] + gsp[528 + r * 33 + 16 + jj]
                    + (double)b_ih[2 * HDIM + g0] + (double)b_hh[2 * HDIM + g0];
    const double go = gsp[r * 33 + 24 + jj] + gsp[528 + r * 33 + 24 + jj]
                    + (double)b_ih[3 * HDIM + g0] + (double)b_hh[3 * HDIM + g0];
    const size_t oidx = (size_t)(r0 + r) * HDIM + g0;
    const double cold = (t == 0) ? 0.0 : cst[oidx];
    const double cn = sigd(gf) * cold + sigd(gi) * tanh(gg);
    const double hn = sigd(go) * tanh(cn);
    cst[oidx] = cn;
    hW[oidx]  = hn;
  }
}

// Phase 2: one batch row per block; fused dual GEMV; row-level skip.
__global__ __launch_bounds__(256) void k_phase2(
    const double* __restrict__ h, const float* __restrict__ wtro,
    const float* __restrict__ b_out, const float* __restrict__ wtrc,
    const float* __restrict__ b_ctrl, const float* __restrict__ noise,
    const int* __restrict__ epoch_p, double* __restrict__ ybar,
    double* __restrict__ preds, float* __restrict__ halt,
    double* __restrict__ ylast, int* __restrict__ rowlive,
    int* __restrict__ alive, int t)
{
  const int tid = threadIdx.x;
  const int b   = blockIdx.x;
  if (t > 0 && rowlive[b] == 0) return;

  __shared__ double hsh[HDIM];
  __shared__ double p1[4][64];
  __shared__ double p2[4][64];
  __shared__ double ysh[64];

  *(double2*)&hsh[2 * tid] = *(const double2*)(h + (size_t)b * HDIM + 2 * tid);
  __syncthreads();

  const int c = tid & 63, kq = tid >> 6;
  const int k0 = kq * 128;

  double s1 = 0.0, s2 = 0.0;
  #pragma unroll 8
  for (int k = k0; k < k0 + 128; ++k) {
    const double hk = hsh[k];
    s1 += hk * (double)wtro[k * 64 + c];
    s2 += hk * (double)wtrc[k * 64 + c];
  }
  p1[kq][c] = s1;
  p2[kq][c] = s2;
  __syncthreads();

  if (tid < 64)
    ysh[tid] = sigd(p1[0][tid] + p1[1][tid] + p1[2][tid] + p1[3][tid]
                    + (double)b_out[tid]);
  __syncthreads();

  if (tid < 64) {
    double a2 = p2[0][tid] + p2[1][tid] + p2[2][tid] + p2[3][tid];
    #pragma unroll 8
    for (int j = 0; j < CDIM; ++j)
      a2 += ysh[j] * (double)wtrc[(512 + j) * 64 + tid];
    a2 += (double)t * (double)wtrc[576 * 64 + tid] + (double)b_ctrl[tid];

    const double eps = exp(-7.0 * (double)(*epoch_p) / 99.0);
    const double pr  = (1.0 - eps) * sigd(a2) + eps * 0.05;
    const double n   = (double)noise[((size_t)t * BBATCH + b) * CDIM + tid];
    const bool   at  = n < pr;
    const double yh  = ysh[tid];
    const size_t i   = (size_t)b * CDIM + tid;

    const double pred_old = (t == 0) ? 0.0  : preds[i];
    const double ybar_old = (t == 0) ? 0.0  : ybar[i];
    const float  halt_old = (t == 0) ? -1.0f : halt[i];

    const double pred_new = (at && pred_old == 0.0) ? yh : pred_old;
    preds[i] = pred_new;
    ybar[i]  = (at && ybar_old == 0.0) ? 1.0 : ybar_old;
    halt[i]  = (halt_old == -1.0f && at) ? (float)t : halt_old;
    ylast[i] = yh;

    const unsigned long long m = __ballot(pred_new == 0.0);
    if (tid == 0) {
      rowlive[b] = (m != 0ull) ? 1 : 0;
      if (m != 0ull) atomicOr(alive + t, 1);
    }
  }
}

__global__ __launch_bounds__(256) void k_final_out(
    const double* __restrict__ preds, const double* __restrict__ ylast,
    float* __restrict__ out)
{
  const int i = blockIdx.x * 256 + threadIdx.x;
  const double p = preds[i];
  out[i] = (float)(p == 0.0 ? ylast[i] : p);
}

__global__ __launch_bounds__(256) void k_final_mean(
    const float* __restrict__ halt, float* __restrict__ out)
{
  __shared__ double s[256];
  double acc = 0.0;
  for (int i = threadIdx.x; i < BBATCH * CDIM; i += 256) {
    const float hp = halt[i];
    acc += 1.0 + (hp == -1.0f ? (double)(TT - 1) : (double)hp);
  }
  s[threadIdx.x] = acc;
  __syncthreads();
  for (int off = 128; off > 0; off >>= 1) {
    if (threadIdx.x < off) s[threadIdx.x] += s[threadIdx.x + off];
    __syncthreads();
  }
  if (threadIdx.x == 0)
    out[BBATCH * CDIM] = (float)(s[0] / (double)(BBATCH * CDIM) / (double)(TT + 1));
}

extern "C" void kernel_launch(void* const* d_in, const int* in_sizes, int n_in,
                              void* d_out, int out_size, void* d_ws, size_t ws_size,
                              hipStream_t stream)
{
  const float* X      = (const float*)d_in[0];
  const float* noise  = (const float*)d_in[1];
  const float* W_ih   = (const float*)d_in[2];
  const float* W_hh   = (const float*)d_in[3];
  const float* b_ih   = (const float*)d_in[4];
  const float* b_hh   = (const float*)d_in[5];
  const float* W_out  = (const float*)d_in[6];
  const float* b_out  = (const float*)d_in[7];
  const float* W_ctrl = (const float*)d_in[8];
  const float* b_ctrl = (const float*)d_in[9];
  const int*   epoch  = (const int*)d_in[10];
  float* out = (float*)d_out;

  char* ws = (char*)d_ws;
  double* h0      = (double*)ws;
  double* h1      = h0    + (size_t)BBATCH * HDIM;
  double* cst     = h1    + (size_t)BBATCH * HDIM;
  double* ybar    = cst   + (size_t)BBATCH * HDIM;
  double* preds   = ybar  + (size_t)BBATCH * CDIM;
  double* ylast   = preds + (size_t)BBATCH * CDIM;
  float*  halt    = (float*)(ylast + (size_t)BBATCH * CDIM);
  float*  wtro    = halt + (size_t)BBATCH * CDIM;
  float*  wtrc    = wtro + (size_t)HDIM * CDIM;
  int*    rowlive = (int*)(wtrc + (size_t)577 * CDIM);
  int*    alive   = rowlive + BBATCH;

  k_init<<<145, 256, 0, stream>>>(wtro, W_out, wtrc, W_ctrl, rowlive, alive);

  for (int t = 0; t < TT; ++t) {
    const double* hR = (t & 1) ? h1 : h0;
    double*       hW = (t & 1) ? h0 : h1;
    k_phase1<<<dim3(64, 16), 256, 0, stream>>>(X, W_ih, W_hh, b_ih, b_hh,
                                               hR, hW, cst, ybar, rowlive, alive, t);
    k_phase2<<<BBATCH, 256, 0, stream>>>(hW, wtro, b_out, wtrc, b_ctrl, noise,
                                         epoch, ybar, preds, halt, ylast,
                                         rowlive, alive, t);
  }

  k_final_out<<<64, 256, 0, stream>>>(preds, ylast, out);
  k_final_mean<<<1, 256, 0, stream>>>(halt, out);
}

// Round 12
// 3879.652 us; speedup vs baseline: 2.0566x; 1.0907x over previous
//
#include <hip/hip_runtime.h>
#include <math.h>

#define TT 400
#define BBATCH 256
#define VDIM 128
#define CDIM 64
#define HDIM 512
#define NCHUNK 11    // 11 chunks x 64 k (2 k-halves of 32)
#define TSPLIT 160   // t >= TSPLIT: merged 1-launch step (provably-dead region)
#define P1B 1024

typedef double d4 __attribute__((ext_vector_type(4)));

__device__ __forceinline__ double sigd(double x) {
  if (x >= 0.0) { double e = exp(-x); return 1.0 / (1.0 + e); }
  double e = exp(x); return e / (1.0 + e);
}

__global__ __launch_bounds__(256) void k_init(
    float* __restrict__ wtro, const float* __restrict__ W_out,
    float* __restrict__ wtrc, const float* __restrict__ W_ctrl,
    int* __restrict__ rowlive, int* __restrict__ alive, int* __restrict__ done)
{
  const int i = blockIdx.x * 256 + threadIdx.x;
  if (i < HDIM * CDIM) {
    const int k = i >> 6, c = i & 63;
    wtro[i] = W_out[c * HDIM + k];
  }
  if (i < 577 * CDIM) {
    const int k = i >> 6, c = i & 63;
    wtrc[i] = W_ctrl[c * 577 + k];
  }
  if (i < BBATCH) rowlive[i] = 1;
  if (i < TT) alive[i] = 0;
  if (i < TT * 16) done[i] = 0;
}

// ---------- shared device helpers (phase-1 body, phase-2 body) ----------

__device__ __forceinline__ void phase1_body(
    const float* __restrict__ X, const float* __restrict__ W_ih,
    const float* __restrict__ W_hh, const float* __restrict__ b_ih,
    const float* __restrict__ b_hh, const double* __restrict__ hR,
    double* __restrict__ hW, double* __restrict__ cst,
    const double* __restrict__ ybar, int t, int cb, int rb, int tid,
    double (*aF)[2][8][66], float (*bF)[2][2][8][68])
{
  const int lane = tid & 63;
  const int wid  = tid >> 6;
  const int r0   = rb * 16;
  const int hbase = cb * 8;

  double* gsp = &aF[0][0][0][0];   // gate staging aliases aF after the k-loop

  const int sA  = tid & 7;          // k-slot
  const int khA = (tid >> 3) & 1;   // k-half
  const int rrA = tid >> 4;         // 0..15: A row / B col

  // Empirical f64-MFMA D-layout probe (see R3): decode reg->row/col.
  int rowm[4], colm[4];
  {
    d4 dp = {0.0, 0.0, 0.0, 0.0};
    const double ap = (lane < 16) ? (double)(lane + 1) : (lane < 32 ? 1.0 : 0.0);
    const double bp = (lane < 16) ? 1.0
                    : (lane < 32 ? 1000.0 * (double)((lane & 15) + 1) : 0.0);
    dp = __builtin_amdgcn_mfma_f64_16x16x4f64(ap, bp, dp, 0, 0, 0);
    #pragma unroll
    for (int r = 0; r < 4; ++r) {
      const int iv = (int)(dp[r] + 0.5);
      rowm[r] = ((iv % 1000) - 1) & 15;
      colm[r] = ((iv / 1000) - 1) & 15;
    }
  }

  double pa[4];
  float4 pw0, pw1;
  const int c0 = rrA, c1 = 16 + rrA;
  const int wg0 = (c0 >> 3) * HDIM + hbase + (c0 & 7);
  const int wg1 = (c1 >> 3) * HDIM + hbase + (c1 & 7);

  auto load_to = [&](int ci) {
    const int kk = ci * 64 + khA * 32 + sA * 4;
    const int rr = r0 + rrA;
    if (kk < VDIM) {
      const float4 v = *(const float4*)(X + ((size_t)t * BBATCH + rr) * VDIM + kk);
      pa[0] = v.x; pa[1] = v.y; pa[2] = v.z; pa[3] = v.w;
    } else if (t == 0) {
      pa[0] = 0.0; pa[1] = 0.0; pa[2] = 0.0; pa[3] = 0.0;
    } else if (kk < VDIM + CDIM) {
      const double2 v0 = *(const double2*)(ybar + (size_t)rr * CDIM + (kk - VDIM));
      const double2 v1 = *(const double2*)(ybar + (size_t)rr * CDIM + (kk - VDIM) + 2);
      pa[0] = v0.x; pa[1] = v0.y; pa[2] = v1.x; pa[3] = v1.y;
    } else {
      const double2 v0 = *(const double2*)(hR + (size_t)rr * HDIM + (kk - 192));
      const double2 v1 = *(const double2*)(hR + (size_t)rr * HDIM + (kk - 192) + 2);
      pa[0] = v0.x; pa[1] = v0.y; pa[2] = v1.x; pa[3] = v1.y;
    }
    pw0 = (kk < 192) ? *(const float4*)(W_ih + (size_t)wg0 * 192 + kk)
                     : *(const float4*)(W_hh + (size_t)wg0 * HDIM + (kk - 192));
    pw1 = (kk < 192) ? *(const float4*)(W_ih + (size_t)wg1 * 192 + kk)
                     : *(const float4*)(W_hh + (size_t)wg1 * HDIM + (kk - 192));
  };
  auto store_to = [&](int buf) {
    #pragma unroll
    for (int j = 0; j < 4; ++j)
      aF[buf][khA][sA][16 * j + rrA] = pa[j];
    *(float4*)&bF[buf][khA][0][sA][rrA * 4] = pw0;
    *(float4*)&bF[buf][khA][1][sA][rrA * 4] = pw1;
  };

  const int ct = wid & 1, kh = wid >> 1;   // wave role
  d4 aa = {0.0, 0.0, 0.0, 0.0}, ab = aa;

  load_to(0);
  store_to(0);
  __syncthreads();

  for (int ci = 0; ci < NCHUNK; ++ci) {
    const int p = ci & 1;
    if (ci + 1 < NCHUNK) load_to(ci + 1);
    #pragma unroll
    for (int ss = 0; ss < 8; ++ss) {
      const double av = aF[p][kh][ss][lane];
      const double bv = (double)bF[p][kh][ct][ss][(lane & 15) * 4 + (lane >> 4)];
      if (ss & 1) ab = __builtin_amdgcn_mfma_f64_16x16x4f64(av, bv, ab, 0, 0, 0);
      else        aa = __builtin_amdgcn_mfma_f64_16x16x4f64(av, bv, aa, 0, 0, 0);
    }
    if (ci + 1 < NCHUNK) store_to(p ^ 1);
    __syncthreads();
  }
  const d4 acc = aa + ab;

  #pragma unroll
  for (int r = 0; r < 4; ++r)
    gsp[kh * 528 + rowm[r] * 33 + 16 * ct + colm[r]] = acc[r];
  __syncthreads();

  if (tid < 128) {
    const int jj = tid & 7, r = tid >> 3;
    const int g0 = hbase + jj;
    const double gi = gsp[r * 33 + jj]      + gsp[528 + r * 33 + jj]
                    + (double)b_ih[0 * HDIM + g0] + (double)b_hh[0 * HDIM + g0];
    const double gf = gsp[r * 33 + 8 + jj]  + gsp[528 + r * 33 + 8 + jj]
                    + (double)b_ih[1 * HDIM + g0] + (double)b_hh[1 * HDIM + g0];
    const double gg = gsp[r * 33 + 16 + jj] + gsp[528 + r * 33 + 16 + jj]
                    + (double)b_ih[2 * HDIM + g0] + (double)b_hh[2 * HDIM + g0];
    const double go = gsp[r * 33 + 24 + jj] + gsp[528 + r * 33 + 24 + jj]
                    + (double)b_ih[3 * HDIM + g0] + (double)b_hh[3 * HDIM + g0];
    const size_t oidx = (size_t)(r0 + r) * HDIM + g0;
    const double cold = (t == 0) ? 0.0 : cst[oidx];
    const double cn = sigd(gf) * cold + sigd(gi) * tanh(gg);
    const double hn = sigd(go) * tanh(cn);
    cst[oidx] = cn;
    hW[oidx]  = hn;
  }
}

__device__ __forceinline__ void phase2_body(
    const double* __restrict__ h, const float* __restrict__ wtro,
    const float* __restrict__ b_out, const float* __restrict__ wtrc,
    const float* __restrict__ b_ctrl, const float* __restrict__ noise,
    const int* __restrict__ epoch_p, double* __restrict__ ybar,
    double* __restrict__ preds, float* __restrict__ halt,
    double* __restrict__ ylast, int* __restrict__ rowlive,
    int* __restrict__ alive, int t, int b, int tid, double* sh)
{
  double* hsh = sh;          // 512
  double* p1  = hsh + HDIM;  // 256
  double* p2  = p1 + 256;    // 256
  double* ysh = p2 + 256;    // 64

  *(double2*)&hsh[2 * tid] = *(const double2*)(h + (size_t)b * HDIM + 2 * tid);
  __syncthreads();

  const int c = tid & 63, kq = tid >> 6;
  const int k0 = kq * 128;

  double s1 = 0.0, s2 = 0.0;
  #pragma unroll 8
  for (int k = k0; k < k0 + 128; ++k) {
    const double hk = hsh[k];
    s1 += hk * (double)wtro[k * 64 + c];
    s2 += hk * (double)wtrc[k * 64 + c];
  }
  p1[kq * 64 + c] = s1;
  p2[kq * 64 + c] = s2;
  __syncthreads();

  if (tid < 64)
    ysh[tid] = sigd(p1[tid] + p1[64 + tid] + p1[128 + tid] + p1[192 + tid]
                    + (double)b_out[tid]);
  __syncthreads();

  if (tid < 64) {
    double a2 = p2[tid] + p2[64 + tid] + p2[128 + tid] + p2[192 + tid];
    #pragma unroll 8
    for (int j = 0; j < CDIM; ++j)
      a2 += ysh[j] * (double)wtrc[(512 + j) * 64 + tid];
    a2 += (double)t * (double)wtrc[576 * 64 + tid] + (double)b_ctrl[tid];

    const double eps = exp(-7.0 * (double)(*epoch_p) / 99.0);
    const double pr  = (1.0 - eps) * sigd(a2) + eps * 0.05;
    const double n   = (double)noise[((size_t)t * BBATCH + b) * CDIM + tid];
    const bool   at  = n < pr;
    const double yh  = ysh[tid];
    const size_t i   = (size_t)b * CDIM + tid;

    const double pred_old = (t == 0) ? 0.0  : preds[i];
    const double ybar_old = (t == 0) ? 0.0  : ybar[i];
    const float  halt_old = (t == 0) ? -1.0f : halt[i];

    const double pred_new = (at && pred_old == 0.0) ? yh : pred_old;
    preds[i] = pred_new;
    ybar[i]  = (at && ybar_old == 0.0) ? 1.0 : ybar_old;
    halt[i]  = (halt_old == -1.0f && at) ? (float)t : halt_old;
    ylast[i] = yh;

    const unsigned long long m = __ballot(pred_new == 0.0);
    if (tid == 0) {
      rowlive[b] = (m != 0ull) ? 1 : 0;
      if (m != 0ull) atomicOr(alive + t, 1);
    }
  }
}

// ---------- t < TSPLIT: proven 2-launch path (R9) ----------

__global__ __launch_bounds__(256, 4) void k_phase1(
    const float* __restrict__ X, const float* __restrict__ W_ih,
    const float* __restrict__ W_hh, const float* __restrict__ b_ih,
    const float* __restrict__ b_hh, const double* __restrict__ hR,
    double* __restrict__ hW, double* __restrict__ cst,
    const double* __restrict__ ybar, const int* __restrict__ rowlive,
    const int* __restrict__ alive, int t)
{
  if (t > 0 && alive[t - 1] == 0) return;
  const int tid = threadIdx.x, lane = tid & 63;
  const int cb = blockIdx.x, rb = blockIdx.y;
  if (t > 0) {
    const unsigned long long m =
        __ballot((lane < 16) && (rowlive[rb * 16 + (lane & 15)] != 0));
    if (m == 0ull) return;
  }
  __shared__ __align__(16) double aF[2][2][8][66];
  __shared__ __align__(16) float  bF[2][2][2][8][68];
  phase1_body(X, W_ih, W_hh, b_ih, b_hh, hR, hW, cst, ybar, t, cb, rb, tid, aF, bF);
}

__global__ __launch_bounds__(256) void k_phase2(
    const double* __restrict__ h, const float* __restrict__ wtro,
    const float* __restrict__ b_out, const float* __restrict__ wtrc,
    const float* __restrict__ b_ctrl, const float* __restrict__ noise,
    const int* __restrict__ epoch_p, double* __restrict__ ybar,
    double* __restrict__ preds, float* __restrict__ halt,
    double* __restrict__ ylast, int* __restrict__ rowlive,
    int* __restrict__ alive, int t)
{
  const int tid = threadIdx.x;
  const int b   = blockIdx.x;
  if (t > 0 && rowlive[b] == 0) return;
  __shared__ double sh[HDIM + 256 + 256 + 64];
  phase2_body(h, wtro, b_out, wtrc, b_ctrl, noise, epoch_p, ybar, preds, halt,
              ylast, rowlive, alive, t, b, tid, sh);
}

// ---------- t >= TSPLIT: merged 1-launch step (dead-region fast path) ----------
// Blocks 0..1023: phase 1 (bump done[t*16+rb] when finished or skipped).
// Blocks 1024..1279: phase 2 for row bid-1024; acquire-load wait on done==64.
// For this dataset t >= TSPLIT is always dead (t* <= 155), so this kernel's
// job is a single cheap early-return launch; the live path is kept correct
// (R10 mechanics, validated) with a lighter polling loop.

__global__ __launch_bounds__(256, 4) void k_tail(
    const float* __restrict__ X, const float* __restrict__ W_ih,
    const float* __restrict__ W_hh, const float* __restrict__ b_ih,
    const float* __restrict__ b_hh, const float* __restrict__ wtro,
    const float* __restrict__ b_out, const float* __restrict__ wtrc,
    const float* __restrict__ b_ctrl, const float* __restrict__ noise,
    const int* __restrict__ epoch_p, const double* __restrict__ hR,
    double* __restrict__ hW, double* __restrict__ cst,
    double* __restrict__ ybar, double* __restrict__ preds,
    float* __restrict__ halt, double* __restrict__ ylast,
    int* __restrict__ rowlive, int* __restrict__ alive,
    int* __restrict__ done, int t)
{
  if (alive[t - 1] == 0) return;               // dead step: everyone leaves

  const int tid  = threadIdx.x;
  const int lane = tid & 63;
  const int bid  = blockIdx.x;

  __shared__ __align__(16) double aF[2][2][8][66];
  __shared__ __align__(16) float  bF[2][2][2][8][68];

  if (bid < P1B) {
    const int cb = bid & 63, rb = bid >> 6;
    const unsigned long long m =
        __ballot((lane < 16) && (rowlive[rb * 16 + (lane & 15)] != 0));
    if (m == 0ull) {
      if (tid == 0) atomicAdd(&done[t * 16 + rb], 1);
      return;
    }
    phase1_body(X, W_ih, W_hh, b_ih, b_hh, hR, hW, cst, ybar, t, cb, rb, tid, aF, bF);
    __syncthreads();
    if (tid == 0) {
      __threadfence();
      atomicAdd(&done[t * 16 + rb], 1);
    }
  } else {
    const int b = bid - P1B;
    if (rowlive[b] == 0) return;
    if (tid == 0) {
      while (__hip_atomic_load(&done[t * 16 + (b >> 4)], __ATOMIC_ACQUIRE,
                               __HIP_MEMORY_SCOPE_AGENT) < 64)
        __builtin_amdgcn_s_sleep(8);
      __threadfence();
    }
    __syncthreads();
    phase2_body(hW, wtro, b_out, wtrc, b_ctrl, noise, epoch_p, ybar, preds, halt,
                ylast, rowlive, alive, t, b, tid, &aF[0][0][0][0]);
  }
}

__global__ __launch_bounds__(256) void k_final_out(
    const double* __restrict__ preds, const double* __restrict__ ylast,
    float* __restrict__ out)
{
  const int i = blockIdx.x * 256 + threadIdx.x;
  const double p = preds[i];
  out[i] = (float)(p == 0.0 ? ylast[i] : p);
}

__global__ __launch_bounds__(256) void k_final_mean(
    const float* __restrict__ halt, float* __restrict__ out)
{
  __shared__ double s[256];
  double acc = 0.0;
  for (int i = threadIdx.x; i < BBATCH * CDIM; i += 256) {
    const float hp = halt[i];
    acc += 1.0 + (hp == -1.0f ? (double)(TT - 1) : (double)hp);
  }
  s[threadIdx.x] = acc;
  __syncthreads();
  for (int off = 128; off > 0; off >>= 1) {
    if (threadIdx.x < off) s[threadIdx.x] += s[threadIdx.x + off];
    __syncthreads();
  }
  if (threadIdx.x == 0)
    out[BBATCH * CDIM] = (float)(s[0] / (double)(BBATCH * CDIM) / (double)(TT + 1));
}

extern "C" void kernel_launch(void* const* d_in, const int* in_sizes, int n_in,
                              void* d_out, int out_size, void* d_ws, size_t ws_size,
                              hipStream_t stream)
{
  const float* X      = (const float*)d_in[0];
  const float* noise  = (const float*)d_in[1];
  const float* W_ih   = (const float*)d_in[2];
  const float* W_hh   = (const float*)d_in[3];
  const float* b_ih   = (const float*)d_in[4];
  const float* b_hh   = (const float*)d_in[5];
  const float* W_out  = (const float*)d_in[6];
  const float* b_out  = (const float*)d_in[7];
  const float* W_ctrl = (const float*)d_in[8];
  const float* b_ctrl = (const float*)d_in[9];
  const int*   epoch  = (const int*)d_in[10];
  float* out = (float*)d_out;

  char* ws = (char*)d_ws;
  double* h0      = (double*)ws;
  double* h1      = h0    + (size_t)BBATCH * HDIM;
  double* cst     = h1    + (size_t)BBATCH * HDIM;
  double* ybar    = cst   + (size_t)BBATCH * HDIM;
  double* preds   = ybar  + (size_t)BBATCH * CDIM;
  double* ylast   = preds + (size_t)BBATCH * CDIM;
  float*  halt    = (float*)(ylast + (size_t)BBATCH * CDIM);
  float*  wtro    = halt + (size_t)BBATCH * CDIM;
  float*  wtrc    = wtro + (size_t)HDIM * CDIM;
  int*    rowlive = (int*)(wtrc + (size_t)577 * CDIM);
  int*    alive   = rowlive + BBATCH;
  int*    done    = alive + TT;

  k_init<<<145, 256, 0, stream>>>(wtro, W_out, wtrc, W_ctrl, rowlive, alive, done);

  for (int t = 0; t < TT; ++t) {
    const double* hR = (t & 1) ? h1 : h0;
    double*       hW = (t & 1) ? h0 : h1;
    if (t < TSPLIT) {
      k_phase1<<<dim3(64, 16), 256, 0, stream>>>(X, W_ih, W_hh, b_ih, b_hh,
                                                 hR, hW, cst, ybar, rowlive, alive, t);
      k_phase2<<<BBATCH, 256, 0, stream>>>(hW, wtro, b_out, wtrc, b_ctrl, noise,
                                           epoch, ybar, preds, halt, ylast,
                                           rowlive, alive, t);
    } else {
      k_tail<<<P1B + BBATCH, 256, 0, stream>>>(
          X, W_ih, W_hh, b_ih, b_hh, wtro, b_out, wtrc, b_ctrl, noise, epoch,
          hR, hW, cst, ybar, preds, halt, ylast, rowlive, alive, done, t);
    }
  }

  k_final_out<<<64, 256, 0, stream>>>(preds, ylast, out);
  k_final_mean<<<1, 256, 0, stream>>>(halt, out);
}